// Round 4
// baseline (223.477 us; speedup 1.0000x reference)
//
#include <hip/hip_runtime.h>
#include <hip/hip_bf16.h>
#include <hip/hip_fp16.h>
#include <stdint.h>

// ---------------------------------------------------------------------------
// CLIPAttentionPooling. R13: 3-deep staging + counted vmcnt (T4).
// R12 post-mortem: store-issue theory wrong (64x overcount). Real structure:
// MFMA 26us + LDS 27us on separate pipes but serialized by the per-step
// vmcnt(0) drain (2 buffers force it). Fix: 3 staging buffers, stage ks+2
// while computing ks, s_waitcnt vmcnt(N>0) so loads stay in flight across
// barriers (AITER/m218 pattern).
//   * s_stats/proj: 256x128 tile, 512 thr / 8 waves (wave tile 64x64 same),
//     3 x 48KB buffers = 144KB LDS, vmcnt(6) steady state.
//   * av: K-chunk 32 (64B rows, no swizzle), 64 steps, 3 x 32KB, vmcnt(4).
// Arithmetic identical to R12 (absmax must not move).
// ---------------------------------------------------------------------------

using half8   = __attribute__((ext_vector_type(8))) _Float16;
using float4v = __attribute__((ext_vector_type(4))) float;
using int4v   = __attribute__((ext_vector_type(4))) int;
using uint2v  = __attribute__((ext_vector_type(2))) unsigned int;

// q/k int16 grid: covers +-6.0, v = QS*(256*hi+lo)
#define QS        (6.0f / 32768.0f)
#define INV_S     (32768.0f / 6.0f)
#define INV_S256  (128.0f / 6.0f)
#define C_HH      (65536.0f * QS * QS)
#define C_X       (256.0f * QS * QS)

// x grid: +-6.0 ; W grid: +-0.25
#define SX        (6.0f / 32768.0f)
#define SW        (0.25f / 32768.0f)
#define P_HH      (65536.0f * SX * SW)
#define P_X       (256.0f * SX * SW)

#define GLOAD_LDS16(gptr, ldsptr)                                              \
  __builtin_amdgcn_global_load_lds(                                            \
      (__attribute__((address_space(1))) void*)(uintptr_t)(gptr),              \
      (__attribute__((address_space(3))) void*)(unsigned)(uintptr_t)(ldsptr),  \
      16, 0, 0)

__device__ __forceinline__ void barrier_raw() {
  asm volatile("" ::: "memory");
  __builtin_amdgcn_s_barrier();
  asm volatile("" ::: "memory");
}

// chunk-level swizzle for the epilogue images (R12-proven).
__device__ __forceinline__ int swz3(int row) {
  return (((row >> 2) & 3) << 1) ^ (row & 3);
}

// ---------------------------------------------------------------------------
// S GEMM + tile softmax stats. Split-i8 16x16x64, 256x128 tile, BK=64,
// 8 waves (4m x 2n of 64x64), 3-deep staging, vmcnt(6).
__global__ __launch_bounds__(512, 2) void gemm_s_stats(
    const int8_t* __restrict__ Ahi, const int8_t* __restrict__ Alo,
    const int8_t* __restrict__ Bhi, const int8_t* __restrict__ Blo,
    _Float16* __restrict__ E, float2* __restrict__ stats)
{
  // [3][ Ah 16K | Al 16K | Bh 8K | Bl 8K ] = 144 KB
  __shared__ __align__(16) int8_t smem[147456];

  const int tid  = threadIdx.x;
  const int wave = tid >> 6;       // 0..7
  const int lane = tid & 63;
  const int quad = lane >> 4;
  const int t16  = lane & 15;
  const int wm   = wave >> 1;      // 0..3 (row wave)
  const int wn   = wave & 1;       // 0..1 (col wave)
  const int row0 = blockIdx.y * 256;
  const int col0 = blockIdx.x * 128;

  const int seg  = lane & 3;
  const int arow = wave * 16 + (lane >> 2);   // 0..127 staging row

  // 32-bit global byte offsets, loop-invariant; +k0 per step.
  const int gA0 = (row0 + arow) * 2048 + seg * 16;
  const int gA1 = gA0 + 128 * 2048;
  const int gB0 = (col0 + arow) * 2048 + seg * 16;
  const int ldsW = wave * 1024;    // uniform per-wave LDS base inside a plane

  int4v hh[4][4], cc[4][4];
#pragma unroll
  for (int i = 0; i < 4; ++i)
#pragma unroll
    for (int j = 0; j < 4; ++j) {
      hh[i][j] = (int4v){0, 0, 0, 0};
      cc[i][j] = (int4v){0, 0, 0, 0};
    }

  // buffer layout: base b*49152; Ah @0 (16K), Al @16384, Bh @32768, Bl @40960
  auto stage_k = [&](int ks, int b) {
    const int k0 = ks * 64;
    int8_t* base = smem + b * 49152;
    GLOAD_LDS16(Ahi + gA0 + k0, base + ldsW);
    GLOAD_LDS16(Ahi + gA1 + k0, base + 8192 + ldsW);
    GLOAD_LDS16(Alo + gA0 + k0, base + 16384 + ldsW);
    GLOAD_LDS16(Alo + gA1 + k0, base + 16384 + 8192 + ldsW);
    GLOAD_LDS16(Bhi + gB0 + k0, base + 32768 + ldsW);
    GLOAD_LDS16(Blo + gB0 + k0, base + 40960 + ldsW);
  };

  stage_k(0, 0);
  stage_k(1, 1);
  asm volatile("s_waitcnt vmcnt(6)" ::: "memory");  // stage(0) landed
  barrier_raw();

  for (int ks = 0; ks < 16; ++ks) {
    int8_t* base = smem + (ks % 3) * 49152;
    if (ks < 14) stage_k(ks + 2, (ks + 2) % 3);

    int4v ah[4], al[4], bh[4], bl[4];
#pragma unroll
    for (int i = 0; i < 4; ++i) {
      const int ao = (wm * 64 + i * 16 + t16) * 64 + quad * 16;
      ah[i] = *(const int4v*)(base + ao);
      al[i] = *(const int4v*)(base + 16384 + ao);
    }
#pragma unroll
    for (int j = 0; j < 4; ++j) {
      const int bo = (wn * 64 + j * 16 + t16) * 64 + quad * 16;
      bh[j] = *(const int4v*)(base + 32768 + bo);
      bl[j] = *(const int4v*)(base + 40960 + bo);
    }

    __builtin_amdgcn_s_setprio(1);
#pragma unroll
    for (int i = 0; i < 4; ++i)
#pragma unroll
      for (int j = 0; j < 4; ++j) {
        hh[i][j] = __builtin_amdgcn_mfma_i32_16x16x64_i8(ah[i], bh[j], hh[i][j], 0, 0, 0);
        cc[i][j] = __builtin_amdgcn_mfma_i32_16x16x64_i8(ah[i], bl[j], cc[i][j], 0, 0, 0);
        cc[i][j] = __builtin_amdgcn_mfma_i32_16x16x64_i8(al[i], bh[j], cc[i][j], 0, 0, 0);
      }
    __builtin_amdgcn_s_setprio(0);

    if (ks < 15) {
      if (ks < 14) asm volatile("s_waitcnt vmcnt(6)" ::: "memory");
      else         asm volatile("s_waitcnt vmcnt(0)" ::: "memory");
      barrier_raw();
    }
  }
  barrier_raw();  // all reads done before LDS reuse below

  // ---- epilogue: tile softmax stats + LDS-image E store -------------------
  // red: 4KB at smem+65536 (buf1 region, dead). img: 64KB at smem[0,65536).
  float* red = (float*)(smem + 65536);

  float vv[4][4][4];
  float rmax[4][4];
#pragma unroll
  for (int i = 0; i < 4; ++i)
#pragma unroll
    for (int r = 0; r < 4; ++r) {
      float mx = -3.0e38f;
#pragma unroll
      for (int j = 0; j < 4; ++j) {
        float v = C_HH * (float)hh[i][j][r] + C_X * (float)cc[i][j][r];
        vv[i][j][r] = v;
        mx = fmaxf(mx, v);
      }
      mx = fmaxf(mx, __shfl_xor(mx, 1));
      mx = fmaxf(mx, __shfl_xor(mx, 2));
      mx = fmaxf(mx, __shfl_xor(mx, 4));
      mx = fmaxf(mx, __shfl_xor(mx, 8));
      rmax[i][r] = mx;
    }
  if (t16 == 0) {
#pragma unroll
    for (int i = 0; i < 4; ++i)
#pragma unroll
      for (int r = 0; r < 4; ++r)
        red[wn * 256 + wm * 64 + i * 16 + quad * 4 + r] = rmax[i][r];
  }
  __syncthreads();

  float mrow[4][4];
#pragma unroll
  for (int i = 0; i < 4; ++i)
#pragma unroll
    for (int r = 0; r < 4; ++r) {
      const int row = wm * 64 + i * 16 + quad * 4 + r;
      mrow[i][r] = fmaxf(red[row], red[256 + row]);
    }

  float rsum[4][4];
#pragma unroll
  for (int i = 0; i < 4; ++i)
#pragma unroll
    for (int r = 0; r < 4; ++r) {
      float s = 0.f;
#pragma unroll
      for (int j = 0; j < 4; ++j) {
        float e = __expf(vv[i][j][r] - mrow[i][r]);
        vv[i][j][r] = e;
        s += e;
      }
      s += __shfl_xor(s, 1);
      s += __shfl_xor(s, 2);
      s += __shfl_xor(s, 4);
      s += __shfl_xor(s, 8);
      rsum[i][r] = s;
    }
  if (t16 == 0) {
#pragma unroll
    for (int i = 0; i < 4; ++i)
#pragma unroll
      for (int r = 0; r < 4; ++r)
        red[512 + wn * 256 + wm * 64 + i * 16 + quad * 4 + r] = rsum[i][r];
  }

  // E fragments -> swizzled u16 image [256][128] over smem[0,65536)
  uint16_t* img = (uint16_t*)smem;
#pragma unroll
  for (int i = 0; i < 4; ++i)
#pragma unroll
    for (int j = 0; j < 4; ++j)
#pragma unroll
      for (int r = 0; r < 4; ++r) {
        const int row  = wm * 64 + i * 16 + quad * 4 + r;
        const int col  = wn * 64 + j * 16 + t16;
        const int colS = col ^ (swz3(row) << 3);
        _Float16 h = (_Float16)vv[i][j][r];
        img[row * 128 + colS] = *(const uint16_t*)&h;
      }
  __syncthreads();

  // coalesced E store: 8 x b128 per thread (512 thr x 8 x 16B = 64KB)
#pragma unroll
  for (int it = 0; it < 8; ++it) {
    const int row    = wave * 32 + it * 4 + quad;
    const int chunkS = t16 ^ swz3(row);
    int4v v = *(const int4v*)&img[row * 128 + chunkS * 8];
    *(int4v*)&E[(size_t)(row0 + row) * 4096 + col0 + t16 * 8] = v;
  }

  if (tid < 256) {
    const float m = fmaxf(red[tid], red[256 + tid]);
    const float l = red[512 + tid] + red[768 + tid];
    stats[(size_t)(row0 + tid) * 32 + blockIdx.x] = make_float2(m, l);
  }
}

// ---------------------------------------------------------------------------
// proj: qk = x Wqk^T + bias. Same 256x128 / 3-deep / vmcnt(6) structure.
__global__ __launch_bounds__(512, 2) void gemm_proj_i8(
    const int8_t* __restrict__ Ahi, const int8_t* __restrict__ Alo,
    const int8_t* __restrict__ Bhi, const int8_t* __restrict__ Blo,
    const float* __restrict__ biasQ, const float* __restrict__ biasK,
    int8_t* __restrict__ Ch, int8_t* __restrict__ Cl)
{
  __shared__ __align__(16) int8_t smem[147456];

  const int tid  = threadIdx.x;
  const int wave = tid >> 6;
  const int lane = tid & 63;
  const int quad = lane >> 4;
  const int t16  = lane & 15;
  const int wm   = wave >> 1;
  const int wn   = wave & 1;
  const int row0 = blockIdx.y * 256;
  const int col0 = blockIdx.x * 128;

  const int seg  = lane & 3;
  const int arow = wave * 16 + (lane >> 2);

  const int gA0 = (row0 + arow) * 1024 + seg * 16;
  const int gA1 = gA0 + 128 * 1024;
  const int gB0 = (col0 + arow) * 1024 + seg * 16;
  const int ldsW = wave * 1024;

  int4v hh[4][4], cc[4][4];
#pragma unroll
  for (int i = 0; i < 4; ++i)
#pragma unroll
    for (int j = 0; j < 4; ++j) {
      hh[i][j] = (int4v){0, 0, 0, 0};
      cc[i][j] = (int4v){0, 0, 0, 0};
    }

  auto stage_k = [&](int ks, int b) {
    const int k0 = ks * 64;
    int8_t* base = smem + b * 49152;
    GLOAD_LDS16(Ahi + gA0 + k0, base + ldsW);
    GLOAD_LDS16(Ahi + gA1 + k0, base + 8192 + ldsW);
    GLOAD_LDS16(Alo + gA0 + k0, base + 16384 + ldsW);
    GLOAD_LDS16(Alo + gA1 + k0, base + 16384 + 8192 + ldsW);
    GLOAD_LDS16(Bhi + gB0 + k0, base + 32768 + ldsW);
    GLOAD_LDS16(Blo + gB0 + k0, base + 40960 + ldsW);
  };

  stage_k(0, 0);
  stage_k(1, 1);
  asm volatile("s_waitcnt vmcnt(6)" ::: "memory");
  barrier_raw();

  for (int ks = 0; ks < 16; ++ks) {
    int8_t* base = smem + (ks % 3) * 49152;
    if (ks < 14) stage_k(ks + 2, (ks + 2) % 3);

    int4v ah[4], al[4], bh[4], bl[4];
#pragma unroll
    for (int i = 0; i < 4; ++i) {
      const int ao = (wm * 64 + i * 16 + t16) * 64 + quad * 16;
      ah[i] = *(const int4v*)(base + ao);
      al[i] = *(const int4v*)(base + 16384 + ao);
    }
#pragma unroll
    for (int j = 0; j < 4; ++j) {
      const int bo = (wn * 64 + j * 16 + t16) * 64 + quad * 16;
      bh[j] = *(const int4v*)(base + 32768 + bo);
      bl[j] = *(const int4v*)(base + 40960 + bo);
    }

    __builtin_amdgcn_s_setprio(1);
#pragma unroll
    for (int i = 0; i < 4; ++i)
#pragma unroll
      for (int j = 0; j < 4; ++j) {
        hh[i][j] = __builtin_amdgcn_mfma_i32_16x16x64_i8(ah[i], bh[j], hh[i][j], 0, 0, 0);
        cc[i][j] = __builtin_amdgcn_mfma_i32_16x16x64_i8(ah[i], bl[j], cc[i][j], 0, 0, 0);
        cc[i][j] = __builtin_amdgcn_mfma_i32_16x16x64_i8(al[i], bh[j], cc[i][j], 0, 0, 0);
      }
    __builtin_amdgcn_s_setprio(0);

    if (ks < 15) {
      if (ks < 14) asm volatile("s_waitcnt vmcnt(6)" ::: "memory");
      else         asm volatile("s_waitcnt vmcnt(0)" ::: "memory");
      barrier_raw();
    }
  }
  barrier_raw();

  // ---- epilogue: quant -> packed u16 image [256][128] -> coalesced stores -
  uint16_t* img = (uint16_t*)smem;
#pragma unroll
  for (int i = 0; i < 4; ++i) {
#pragma unroll
    for (int j = 0; j < 4; ++j) {
      const int ccol = col0 + wn * 64 + j * 16 + t16;
      const float* bp = (ccol < 1024) ? biasQ : (biasK - 1024);
#pragma unroll
      for (int r = 0; r < 4; ++r) {
        float v = P_HH * (float)hh[i][j][r] + P_X * (float)cc[i][j][r] + bp[ccol];
        int hi = (int)lrintf(v * INV_S256);
        hi = hi > 127 ? 127 : (hi < -127 ? -127 : hi);
        int lo = (int)lrintf(v * INV_S - 256.0f * (float)hi);
        lo = lo > 127 ? 127 : (lo < -127 ? -127 : lo);
        const int row  = wm * 64 + i * 16 + quad * 4 + r;
        const int col  = wn * 64 + j * 16 + t16;
        const int colS = col ^ (swz3(row) << 3);
        img[row * 128 + colS] = (uint16_t)((hi & 0xff) | ((lo & 0xff) << 8));
      }
    }
  }
  __syncthreads();

#pragma unroll
  for (int it = 0; it < 8; ++it) {
    const int row    = wave * 32 + it * 4 + quad;
    const int chunkS = t16 ^ swz3(row);
    int4v p = *(const int4v*)&img[row * 128 + chunkS * 8];
    const unsigned w0 = (unsigned)p[0], w1 = (unsigned)p[1];
    const unsigned w2 = (unsigned)p[2], w3 = (unsigned)p[3];
    uint2v hw, lw;
    hw[0] = (w0 & 0xffu) | (((w0 >> 16) & 0xffu) << 8) |
            ((w1 & 0xffu) << 16) | (((w1 >> 16) & 0xffu) << 24);
    hw[1] = (w2 & 0xffu) | (((w2 >> 16) & 0xffu) << 8) |
            ((w3 & 0xffu) << 16) | (((w3 >> 16) & 0xffu) << 24);
    lw[0] = ((w0 >> 8) & 0xffu) | (((w0 >> 24) & 0xffu) << 8) |
            (((w1 >> 8) & 0xffu) << 16) | ((w1 >> 24) << 24);
    lw[1] = ((w2 >> 8) & 0xffu) | (((w2 >> 24) & 0xffu) << 8) |
            (((w3 >> 8) & 0xffu) << 16) | ((w3 >> 24) << 24);
    const size_t go = (size_t)(row0 + row) * 2048 + col0 + t16 * 8;
    *(uint2v*)&Ch[go] = hw;
    *(uint2v*)&Cl[go] = lw;
  }
}

// ---------------------------------------------------------------------------
// AV: out = sum_t beta_t (E_t x). 512 thr, in-block split-K=2 (z = wave>>2).
// R13: K-chunk 32 halves (64B rows, linear), 64 steps, 3-deep, vmcnt(4).
__global__ __launch_bounds__(512) void gemm_av(
    const uint16_t* __restrict__ E, const uint16_t* __restrict__ B,
    const float2* __restrict__ stats, float* __restrict__ out)
{
  // [b][ z*8192 + (A 4096 | B 4096) ] u16 = 3 x 32 KB
  __shared__ __align__(16) uint16_t stg[3][16384];
  __shared__ float betaS[128 * 33];

  const int L      = blockIdx.x;        // 0..255
  const int xcd    = L & 7;
  const int rest   = L >> 3;            // 0..31
  const int colb   = rest & 7;          // 0..7
  const int bandHi = rest >> 3;         // 0..3
  const int band   = xcd + 8 * bandHi;  // 0..31
  const int row0   = band * 128;
  const int col0   = colb * 128;

  const int tid  = threadIdx.x;
  const int wave = tid >> 6;
  const int z    = wave >> 2;           // 0..1 K-half
  const int gw   = wave & 3;            // group-local wave
  const int lane = tid & 63;
  const int quad = lane >> 4;
  const int t16  = lane & 15;
  const int wm   = gw & 1;
  const int wn   = gw >> 1;

  const int seg  = lane & 3;
  const int grow = gw * 16 + (lane >> 2);   // 0..63 staging row

  // u16 offsets, loop-invariant; +k0h per step.
  const int offA0 = (row0 + grow) * 4096 + seg * 8;
  const int offA1 = offA0 + 64 * 4096;
  const int offB0 = (col0 + grow) * 4096 + seg * 8;
  const int offB1 = offB0 + 64 * 4096;
  const int ldsW  = gw * 512;           // uniform u16 base per wave

  auto stage_s = [&](int s, int b) {
    const int k0h = (z * 16 + (s >> 2)) * 128 + (s & 3) * 32;
    uint16_t* dst = &stg[b][z * 8192];
    GLOAD_LDS16(E + offA0 + k0h, dst + ldsW);
    GLOAD_LDS16(E + offA1 + k0h, dst + 2048 + ldsW);
    GLOAD_LDS16(B + offB0 + k0h, dst + 4096 + ldsW);
    GLOAD_LDS16(B + offB1 + k0h, dst + 4096 + 2048 + ldsW);
  };

  stage_s(0, 0);
  stage_s(1, 1);

  // ---- beta prologue: threads 0..127, one row each ------------------------
  if (tid < 128) {
    const int row = row0 + tid;
    float2 st[32];
    float m = -3.0e38f;
#pragma unroll
    for (int t = 0; t < 32; ++t) {
      st[t] = stats[(size_t)row * 32 + t];
      m = fmaxf(m, st[t].x);
    }
    float l = 0.f;
#pragma unroll
    for (int t = 0; t < 32; ++t) l += st[t].y * __expf(st[t].x - m);
    const float inv = 1.0f / l;
#pragma unroll
    for (int t = 0; t < 32; ++t)
      betaS[tid * 33 + t] = __expf(st[t].x - m) * inv;
  }
  asm volatile("s_waitcnt vmcnt(4)" ::: "memory");  // stage(0) landed
  __syncthreads();

  float4v acc[4][4];
#pragma unroll
  for (int i = 0; i < 4; ++i)
#pragma unroll
    for (int j = 0; j < 4; ++j)
      acc[i][j] = (float4v){0.f, 0.f, 0.f, 0.f};

  for (int s = 0; s < 64; ++s) {
    const uint16_t* base = &stg[s % 3][z * 8192];
    if (s < 62) stage_s(s + 2, (s + 2) % 3);

    const int t = z * 16 + (s >> 2);
    _Float16 bb[4];
#pragma unroll
    for (int i = 0; i < 4; ++i)
      bb[i] = (_Float16)betaS[(wm * 64 + i * 16 + t16) * 33 + t];

    half8 af[4], bf[4];
#pragma unroll
    for (int i = 0; i < 4; ++i) {
      af[i] = *(const half8*)&base[(wm * 64 + i * 16 + t16) * 32 + quad * 8];
      half8 bs;
#pragma unroll
      for (int c = 0; c < 8; ++c) bs[c] = bb[i];
      af[i] = af[i] * bs;
    }
#pragma unroll
    for (int j = 0; j < 4; ++j)
      bf[j] = *(const half8*)&base[4096 + (wn * 64 + j * 16 + t16) * 32 + quad * 8];

    __builtin_amdgcn_s_setprio(1);
#pragma unroll
    for (int i = 0; i < 4; ++i)
#pragma unroll
      for (int j = 0; j < 4; ++j)
        acc[i][j] = __builtin_amdgcn_mfma_f32_16x16x32_f16(af[i], bf[j], acc[i][j], 0, 0, 0);
    __builtin_amdgcn_s_setprio(0);

    if (s < 63) {
      if (s < 62) asm volatile("s_waitcnt vmcnt(4)" ::: "memory");
      else        asm volatile("s_waitcnt vmcnt(0)" ::: "memory");
      barrier_raw();
    }
  }
  barrier_raw();  // all reads done before LDS reuse

  // ---- combine group1 -> group0 via LDS (two 16 KB halves) ----------------
  float* xfer = (float*)stg;  // 8192 floats = 32 KB = buf0, dead
#pragma unroll
  for (int h = 0; h < 2; ++h) {
    if (z == 1) {
#pragma unroll
      for (int i = 2 * h; i < 2 * h + 2; ++i)
#pragma unroll
        for (int j = 0; j < 4; ++j)
#pragma unroll
          for (int r = 0; r < 4; ++r) {
            const int e = (i - 2 * h) * 16 + j * 4 + r;
            xfer[e * 256 + gw * 64 + lane] = acc[i][j][r];
          }
    }
    __syncthreads();
    if (z == 0) {
#pragma unroll
      for (int i = 2 * h; i < 2 * h + 2; ++i)
#pragma unroll
        for (int j = 0; j < 4; ++j)
#pragma unroll
          for (int r = 0; r < 4; ++r) {
            const int e = (i - 2 * h) * 16 + j * 4 + r;
            acc[i][j][r] += xfer[e * 256 + gw * 64 + lane];
          }
    }
    __syncthreads();
  }

  // ---- fp32 image store: z=0 writes image, ALL 512 threads store ----------
  float* img = (float*)stg;  // [128][128] f32 = 64 KB over buf0+buf1
  if (z == 0) {
#pragma unroll
    for (int i = 0; i < 4; ++i)
#pragma unroll
      for (int j = 0; j < 4; ++j)
#pragma unroll
        for (int r = 0; r < 4; ++r) {
          const int row  = wm * 64 + i * 16 + quad * 4 + r;
          const int col  = wn * 64 + j * 16 + t16;
          const int colS = col ^ (((quad << 1) ^ r) << 2);
          img[row * 128 + colS] = acc[i][j][r];
        }
  }
  __syncthreads();

#pragma unroll
  for (int it = 0; it < 8; ++it) {
    const int row    = wave * 16 + (lane >> 2);
    const int chunk  = (lane & 3) * 8 + it;          // 32 chunks of 4 floats
    const int chunkS = chunk ^ swz3(row);
    float4v v = *(const float4v*)&img[row * 128 + chunkS * 4];
    *(float4v*)&out[(size_t)(row0 + row) * 1024 + col0 + chunk * 4] = v;
  }
}

// ---------------------------------------------------------------------------
// Fused quant + transpose-cast (unchanged).
__global__ __launch_bounds__(256) void quantT(
    const float* __restrict__ x, const float* __restrict__ Wq,
    const float* __restrict__ Wk,
    int8_t* __restrict__ xhi, int8_t* __restrict__ xlo,
    int8_t* __restrict__ whi, int8_t* __restrict__ wlo,
    uint16_t* __restrict__ xT)
{
  if (blockIdx.x < 6144) {
    int i = blockIdx.x * 256 + threadIdx.x;  // 0..1572863
    const float* src; int8_t* dh; int8_t* dl; int idx; float s256, s;
    if (i < 1048576)      { src = x;  idx = i;           dh = xhi; dl = xlo;
                            s256 = INV_S256; s = INV_S; }
    else if (i < 1310720) { src = Wq; idx = i - 1048576; dh = whi; dl = wlo;
                            s256 = 512.0f; s = 131072.0f; }
    else                  { src = Wk; idx = i - 1310720; dh = whi + 1048576;
                            dl = wlo + 1048576; s256 = 512.0f; s = 131072.0f; }
    float4 v = ((const float4*)src)[idx];
    float vv[4] = {v.x, v.y, v.z, v.w};
    int hp = 0, lp = 0;
#pragma unroll
    for (int c = 0; c < 4; ++c) {
      int h = (int)lrintf(vv[c] * s256);
      h = h > 127 ? 127 : (h < -127 ? -127 : h);
      int l = (int)lrintf(vv[c] * s - 256.0f * (float)h);
      l = l > 127 ? 127 : (l < -127 ? -127 : l);
      hp |= (h & 0xff) << (8 * c);
      lp |= (l & 0xff) << (8 * c);
    }
    ((int*)dh)[idx] = hp;
    ((int*)dl)[idx] = lp;
  } else {
    __shared__ float tile[32][33];
    const int tb = blockIdx.x - 6144;   // 0..4095
    const int bx = tb & 31;             // D/32
    const int by = tb >> 5;             // N/32
    const int tx = threadIdx.x & 31;
    const int ty = threadIdx.x >> 5;    // 0..7
#pragma unroll
    for (int p = 0; p < 4; ++p) {
      const int row = by * 32 + ty + p * 8;
      tile[ty + p * 8][tx] = x[(size_t)row * 1024 + bx * 32 + tx];
    }
    __syncthreads();
#pragma unroll
    for (int p = 0; p < 4; ++p) {
      const int oc = ty + p * 8;  // local col in x == local row in xT
      __half hv = __float2half_rn(tile[tx][oc]);
      xT[(size_t)(bx * 32 + oc) * 4096 + by * 32 + tx] = *(uint16_t*)&hv;
    }
  }
}

extern "C" void kernel_launch(void* const* d_in, const int* in_sizes, int n_in,
                              void* d_out, int out_size, void* d_ws, size_t ws_size,
                              hipStream_t stream) {
  const int N = 4096, D = 1024;
  const float* x  = (const float*)d_in[0];
  const float* Wq = (const float*)d_in[1];
  const float* bq = (const float*)d_in[2];
  const float* Wk = (const float*)d_in[3];
  const float* bk = (const float*)d_in[4];
  float* out = (float*)d_out;

  // workspace layout (MiB offsets)
  char* w = (char*)d_ws;
  const size_t MiB = 1024 * 1024;
  int8_t*    xq_hi  = (int8_t*)   (w + 0  * MiB);  // [N x D]
  int8_t*    xq_lo  = (int8_t*)   (w + 4  * MiB);
  int8_t*    Wqk_hi = (int8_t*)   (w + 8  * MiB);  // [2048 x D]
  int8_t*    Wqk_lo = (int8_t*)   (w + 10 * MiB);
  int8_t*    qk_hi  = (int8_t*)   (w + 12 * MiB);  // [N x 2048]
  int8_t*    qk_lo  = (int8_t*)   (w + 20 * MiB);
  _Float16*  E      = (_Float16*) (w + 36 * MiB);  // [N x N] fp16, 32 MiB
  float2*    stats  = (float2*)   (w + 68 * MiB);  // [N x 32] (m,l), 1 MiB
  uint16_t*  xTh    = (uint16_t*) (w + 72 * MiB);  // [D x N] fp16
  // total 80 MiB

  // 1) fused quantization + transpose-cast  (6144 + 4096 blocks)
  quantT<<<10240, 256, 0, stream>>>(x, Wq, Wk, xq_hi, xq_lo, Wqk_hi, Wqk_lo,
                                    xTh);

  // 2) fused qk projection: 256x128 tiles, 512 thr
  gemm_proj_i8<<<dim3(2048 / 128, N / 256), 512, 0, stream>>>(
      xq_hi, xq_lo, Wqk_hi, Wqk_lo, bq, bk, qk_hi, qk_lo);

  // 3) S = q k^T + tile softmax stats -> E fp16, stats (m_t, l_t)
  gemm_s_stats<<<dim3(N / 128, N / 256), 512, 0, stream>>>(
      qk_hi, qk_lo, qk_hi + 1024, qk_lo + 1024, E, stats);

  // 4) out = sum_t beta_t (E_t x): beta prologue + in-block split-K=2
  gemm_av<<<256, 512, 0, stream>>>((const uint16_t*)E, xTh, stats, out);

  (void)in_sizes; (void)n_in; (void)out_size; (void)ws_size;
}